// Round 4
// baseline (78.282 us; speedup 1.0000x reference)
//
#include <hip/hip_runtime.h>
#include <math.h>

// DetectionLoss: masked pairwise IoU + exact Hungarian + scalar loss.
//
// r4 structure: one FUSED kernel, one wave per (image,class) subproblem
// (cost nonzero only for same-class valid pairs -> exact decomposition).
//   - NZ filtering: rows/cols with no positive-IoU entry dropped (exact).
//   - Greedy column-reduction init (classic JV preprocessing): v[j] =
//     min_i c[i,j], assign argmin rows greedily; duals stay feasible,
//     complementary slackness holds -> augmenting only for leftover rows.
//   - JV shortest-augmenting-path, prefer-unmatched tie-break, ALL state
//     in registers (one column per lane); DPP-butterfly 64-lane argmin.
//   - Finalize fused: workers release a flag (ws poisoned to 0xAA != 1
//     each launch), block 0 acquire-polls all flags then reduces the loss.

constexpr int BIMG = 8;
constexpr int NBOX = 200;
constexpr int NCLS = 5;
constexpr int NBLK = BIMG * NCLS;
constexpr float SCORE_THR = 0.001f;

__device__ __forceinline__ unsigned fkey(float f) {
    unsigned u = __float_as_uint(f);
    return (u & 0x80000000u) ? ~u : (u | 0x80000000u);
}
__device__ __forceinline__ float fkey_inv(unsigned k) {
    unsigned u = (k & 0x80000000u) ? (k ^ 0x80000000u) : ~k;
    return __uint_as_float(u);
}

// one lexicographic-min step on (ik, ip); CTRL must be a literal.
#define ARGMIN_DPP_STEP(CTRL)                                                \
    {                                                                        \
        unsigned ok = (unsigned)__builtin_amdgcn_update_dpp(                 \
            (int)ik, (int)ik, (CTRL), 0xF, 0xF, false);                      \
        unsigned op = (unsigned)__builtin_amdgcn_update_dpp(                 \
            (int)ip, (int)ip, (CTRL), 0xF, 0xF, false);                      \
        bool lt = (ok < ik) || ((ok == ik) && (op < ip));                    \
        ik = lt ? ok : ik;                                                   \
        ip = lt ? op : ip;                                                   \
    }

__global__ void __launch_bounds__(64)
det_fused_kernel(const float* __restrict__ boxes1,
                 const float* __restrict__ boxes2,
                 float* __restrict__ sum_part,
                 int* __restrict__ m1_part, int* __restrict__ m2_part,
                 int* __restrict__ flags,
                 float* __restrict__ out)
{
    const int lane = threadIdx.x;
    const int blk  = blockIdx.x;
    const int b    = blk / NCLS;
    const int ci   = blk % NCLS;
    const int cls  = (ci == 0) ? 1 : (ci == 1) ? 2 : (ci == 2) ? 3 : (ci == 3) ? 5 : 7;

    __shared__ float r1x1[NBOX], r1y1[NBOX], r1x2[NBOX], r1y2[NBOX], r1a[NBOX];
    __shared__ float r2x1[NBOX], r2y1[NBOX], r2x2[NBOX], r2y2[NBOX], r2a[NBOX];
    // fallback-only JV state (n > 64; practically unreachable)
    __shared__ float uarr[NBOX + 1], varr[NBOX + 1], minvarr[NBOX + 1];
    __shared__ int   wayarr[NBOX + 1], parr[NBOX + 1], usedarr[NBOX + 1];

    const float* g1 = boxes1 + (size_t)b * NBOX * 6;
    const float* g2 = boxes2 + (size_t)b * NBOX * 6;
    const unsigned long long ltmask = (1ull << lane) - 1ull;

    // ---- phase 1: filter to this class, ballot-compact into LDS
    int m1 = 0, m2 = 0;
    for (int c0 = 0; c0 < NBOX; c0 += 64) {
        int t = c0 + lane;
        bool in = (t < NBOX);
        float x1 = 0, y1 = 0, x2 = 0, y2 = 0, sc = 0, cf = 0;
        if (in) {
            const float2* p = (const float2*)(g1 + (size_t)t * 6);
            float2 q0 = p[0], q1 = p[1], q2 = p[2];
            x1 = q0.x; y1 = q0.y; x2 = q1.x; y2 = q1.y; sc = q2.x; cf = q2.y;
        }
        bool pr = in && (sc > SCORE_THR) && ((int)cf == cls);
        unsigned long long mk = __ballot(pr);
        int pos = m1 + __popcll(mk & ltmask);
        if (pr) { r1x1[pos] = x1; r1y1[pos] = y1; r1x2[pos] = x2; r1y2[pos] = y2;
                  r1a[pos] = (x2 - x1) * (y2 - y1); }
        m1 += __popcll(mk);

        if (in) {
            const float2* p = (const float2*)(g2 + (size_t)t * 6);
            float2 q0 = p[0], q1 = p[1], q2 = p[2];
            x1 = q0.x; y1 = q0.y; x2 = q1.x; y2 = q1.y; sc = q2.x; cf = q2.y;
        }
        pr = in && (sc > SCORE_THR) && ((int)cf == cls);
        mk = __ballot(pr);
        pos = m2 + __popcll(mk & ltmask);
        if (pr) { r2x1[pos] = x1; r2y1[pos] = y1; r2x2[pos] = x2; r2y2[pos] = y2;
                  r2a[pos] = (x2 - x1) * (y2 - y1); }
        m2 += __popcll(mk);
    }
    __syncthreads();

    float blockContrib = 0.f;

    do {
        if (m1 == 0 || m2 == 0) break;
        const int n = (m1 > m2) ? m1 : m2;

        if (n <= 64) {
            // ===================== register fast path =====================
            const bool swapped = (m1 > m2);   // rows = smaller side
            float* rrx1 = swapped ? r2x1 : r1x1; float* rry1 = swapped ? r2y1 : r1y1;
            float* rrx2 = swapped ? r2x2 : r1x2; float* rry2 = swapped ? r2y2 : r1y2;
            float* rra  = swapped ? r2a  : r1a;
            float* ccx1 = swapped ? r1x1 : r2x1; float* ccy1 = swapped ? r1y1 : r2y1;
            float* ccx2 = swapped ? r1x2 : r2x2; float* ccy2 = swapped ? r1y2 : r2y2;
            float* cca  = swapped ? r1a  : r2a;
            int mr = swapped ? m2 : m1;
            int mc = swapped ? m1 : m2;

            float rbx1 = 0, rby1 = 0, rbx2 = 0, rby2 = 0, rba = 0;
            if (lane < mr) { rbx1 = rrx1[lane]; rby1 = rry1[lane]; rbx2 = rrx2[lane];
                             rby2 = rry2[lane]; rba = rra[lane]; }
            float cbx1 = 0, cby1 = 0, cbx2 = 0, cby2 = 0, cba = 0;
            if (lane < mc) { cbx1 = ccx1[lane]; cby1 = ccy1[lane]; cbx2 = ccx2[lane];
                             cby2 = ccy2[lane]; cba = cca[lane]; }

            // ---- NZ scan
            unsigned long long rowmask = 0ull;
            bool colnz = false;
            for (int i = 0; i < mr; ++i) {
                float ax1 = rrx1[i], ay1 = rry1[i], ax2 = rrx2[i], ay2 = rry2[i];
                float iw = fminf(ax2, cbx2) - fmaxf(ax1, cbx1);
                float ih = fminf(ay2, cby2) - fmaxf(ay1, cby1);
                bool nz = (lane < mc) && (iw > 0.f) && (ih > 0.f);
                unsigned long long bal = __ballot(nz);
                if (bal) rowmask |= (1ull << i);
                colnz |= nz;
            }
            int mrP = __popcll(rowmask);
            if (mrP == 0) break;
            unsigned long long colmask = __ballot(colnz);
            int mcP = __popcll(colmask);

            // ---- compact kept rows/cols (in-place LDS), reload regs
            __syncthreads();
            if (lane < mr && ((rowmask >> lane) & 1ull)) {
                int pos = __popcll(rowmask & ltmask);
                rrx1[pos] = rbx1; rry1[pos] = rby1; rrx2[pos] = rbx2; rry2[pos] = rby2;
                rra[pos] = rba;
            }
            if (lane < mc && ((colmask >> lane) & 1ull)) {
                int pos = __popcll(colmask & ltmask);
                ccx1[pos] = cbx1; ccy1[pos] = cby1; ccx2[pos] = cbx2; ccy2[pos] = cby2;
                cca[pos] = cba;
            }
            __syncthreads();
            rbx1 = rby1 = rbx2 = rby2 = rba = 0.f;
            if (lane < mrP) { rbx1 = rrx1[lane]; rby1 = rry1[lane]; rbx2 = rrx2[lane];
                              rby2 = rry2[lane]; rba = rra[lane]; }
            cbx1 = cby1 = cbx2 = cby2 = cba = 0.f;
            if (lane < mcP) { cbx1 = ccx1[lane]; cby1 = ccy1[lane]; cbx2 = ccx2[lane];
                              cby2 = ccy2[lane]; cba = cca[lane]; }
            if (mrP > mcP) {   // re-orient so rows <= cols
                float t;
                t = rbx1; rbx1 = cbx1; cbx1 = t;  t = rby1; rby1 = cby1; cby1 = t;
                t = rbx2; rbx2 = cbx2; cbx2 = t;  t = rby2; rby2 = cby2; cby2 = t;
                t = rba;  rba  = cba;  cba  = t;
                int ti = mrP; mrP = mcP; mcP = ti;
            }

            // ---- column reduction: v[j] = min_i c[i,j], argmin row per col
            float cmin = INFINITY; int cargmin = 0;
            for (int i = 0; i < mrP; ++i) {
                float rx1 = __shfl(rbx1, i), ry1 = __shfl(rby1, i);
                float rx2 = __shfl(rbx2, i), ry2 = __shfl(rby2, i);
                float ra  = __shfl(rba,  i);
                float iw = fmaxf(fminf(rx2, cbx2) - fmaxf(rx1, cbx1), 0.f);
                float ih = fmaxf(fminf(ry2, cby2) - fmaxf(ry1, cby1), 0.f);
                float inter = iw * ih;
                float c = (lane < mcP) ? (-(inter / (ra + cba - inter))) : 0.f;
                if (c < cmin) { cmin = c; cargmin = i; }
            }

            // ---- greedy assignment (scalar serial pass, uniform)
            unsigned long long rowfree = (mrP >= 64) ? ~0ull : ((1ull << mrP) - 1ull);
            unsigned long long amask = 0ull;
            for (int j = 0; j < mcP; ++j) {
                int i = __builtin_amdgcn_readlane(cargmin, j);
                if ((rowfree >> i) & 1ull) { rowfree &= ~(1ull << i); amask |= (1ull << j); }
            }

            // apply per-lane: duals + greedy matches (+ matched-row boxes)
            float vj = (lane < mcP) ? cmin : 0.f;
            float urow = 0.f;
            int   pmrow = 0;
            float cmx1 = 0, cmy1 = 0, cmx2 = 0, cmy2 = 0, cma = 0;
            {
                bool gm = (lane < mcP) && ((amask >> lane) & 1ull);
                float gx1 = __shfl(rbx1, cargmin), gy1 = __shfl(rby1, cargmin);
                float gx2 = __shfl(rbx2, cargmin), gy2 = __shfl(rby2, cargmin);
                float gar = __shfl(rba,  cargmin);
                if (gm) { pmrow = cargmin + 1;
                          cmx1 = gx1; cmy1 = gy1; cmx2 = gx2; cmy2 = gy2; cma = gar; }
            }

            // ---- JV augmenting for remaining free rows
            for (int i = 1; i <= mrP; ++i) {
                if (!((rowfree >> (i - 1)) & 1ull)) continue;

                float rootx1 = __shfl(rbx1, i - 1), rooty1 = __shfl(rby1, i - 1);
                float rootx2 = __shfl(rbx2, i - 1), rooty2 = __shfl(rby2, i - 1);
                float roota  = __shfl(rba,  i - 1);
                float rx1 = rootx1, ry1 = rooty1, rx2 = rootx2, ry2 = rooty2, ra = roota;
                float u0 = 0.f, u_free = 0.f, minvj = INFINITY;
                int   wayj = 0, j0cur = 0, j0n = 0;
                bool  usedj = (lane >= mcP);
                bool  found = false;

                for (int guard = 0; guard <= 66; ++guard) {
                    float iou = 0.f;
                    if (lane < mcP) {
                        float iw = fmaxf(fminf(rx2, cbx2) - fmaxf(rx1, cbx1), 0.f);
                        float ih = fmaxf(fminf(ry2, cby2) - fmaxf(ry1, cby1), 0.f);
                        float inter = iw * ih;
                        iou = inter / (ra + cba - inter);
                    }
                    float cur = -iou - u0 - vj;
                    if (!usedj && cur < minvj) { minvj = cur; wayj = j0cur; }

                    unsigned ik = usedj ? 0xFFFFFFFFu : fkey(minvj);
                    unsigned ip = usedj ? 0xFFFFFFFFu
                                        : ((pmrow ? 0x100u : 0u) | (unsigned)(lane + 1));
                    ARGMIN_DPP_STEP(0xB1)   // quad_perm xor1
                    ARGMIN_DPP_STEP(0x4E)   // quad_perm xor2
                    ARGMIN_DPP_STEP(0x141)  // row_half_mirror
                    ARGMIN_DPP_STEP(0x140)  // row_mirror
                    ARGMIN_DPP_STEP(0x142)  // row_bcast15
                    ARGMIN_DPP_STEP(0x143)  // row_bcast31 -> lane 63 = global min
                    unsigned sk = (unsigned)__builtin_amdgcn_readlane((int)ik, 63);
                    unsigned sp = (unsigned)__builtin_amdgcn_readlane((int)ip, 63);
                    float delta = fkey_inv(sk);
                    j0n = (int)(sp & 0xFFu);
                    bool j0matched = (sp & 0x100u) != 0u;
                    if (j0n == 0xFF) break;   // defensive

                    u_free += delta;
                    if (usedj) { vj -= delta; if (pmrow) urow += delta; }
                    else       { minvj -= delta; }

                    if (!j0matched) { found = true; break; }

                    if (lane == j0n - 1) usedj = true;
                    u0  = __shfl(urow, j0n - 1);
                    rx1 = __shfl(cmx1, j0n - 1); ry1 = __shfl(cmy1, j0n - 1);
                    rx2 = __shfl(cmx2, j0n - 1); ry2 = __shfl(cmy2, j0n - 1);
                    ra  = __shfl(cma,  j0n - 1);
                    j0cur = j0n;
                }

                if (found) {
                    int jj = j0n;
                    for (int hop = 0; hop < 66 && jj != 0; ++hop) {
                        int j1 = __shfl(wayj, jj - 1);
                        if (j1 == 0) {
                            if (lane == jj - 1) {
                                pmrow = i; urow = u_free;
                                cmx1 = rootx1; cmy1 = rooty1; cmx2 = rootx2;
                                cmy2 = rooty2; cma = roota;
                            }
                            jj = 0;
                        } else {
                            int   ppj = __shfl(pmrow, j1 - 1);
                            float pur = __shfl(urow,  j1 - 1);
                            float px1 = __shfl(cmx1, j1 - 1), py1 = __shfl(cmy1, j1 - 1);
                            float px2 = __shfl(cmx2, j1 - 1), py2 = __shfl(cmy2, j1 - 1);
                            float pa  = __shfl(cma,  j1 - 1);
                            if (lane == jj - 1) {
                                pmrow = ppj; urow = pur;
                                cmx1 = px1; cmy1 = py1; cmx2 = px2; cmy2 = py2; cma = pa;
                            }
                            jj = j1;
                        }
                    }
                }
            }

            // ---- matched IoU sum
            float contrib = 0.f;
            if (lane < mcP && pmrow != 0) {
                float iw = fmaxf(fminf(cmx2, cbx2) - fmaxf(cmx1, cbx1), 0.f);
                float ih = fmaxf(fminf(cmy2, cby2) - fmaxf(cmy1, cby1), 0.f);
                float inter = iw * ih;
                contrib = inter / (cma + cba - inter);
            }
            #pragma unroll
            for (int off = 32; off; off >>= 1) contrib += __shfl_xor(contrib, off);
            blockContrib = contrib;
        } else {
            // ===================== LDS fallback (n > 64) ==================
            for (int j = lane; j <= n; j += 64) { varr[j] = 0.f; parr[j] = 0; uarr[j] = 0.f; }
            __syncthreads();

            int j0 = 0;
            for (int i = 1; i <= n; ++i) {
                if (lane == 0) parr[0] = i;
                for (int j = lane; j <= n; j += 64) { minvarr[j] = INFINITY; usedarr[j] = 0; }
                j0 = 0;
                __syncthreads();

                for (int it = 0; it <= n + 1; ++it) {
                    if (lane == 0) usedarr[j0] = 1;
                    __syncthreads();
                    const int i0 = parr[j0];
                    const float u0 = uarr[i0];
                    const bool rowReal = (i0 <= m1);
                    float rx1 = 0, ry1 = 0, rx2 = 0, ry2 = 0, ra = 0;
                    if (rowReal) { rx1 = r1x1[i0-1]; ry1 = r1y1[i0-1]; rx2 = r1x2[i0-1];
                                   ry2 = r1y2[i0-1]; ra = r1a[i0-1]; }
                    for (int j = lane; j <= n; j += 64) {
                        if (j >= 1 && !usedarr[j]) {
                            float cost = 0.f;
                            if (rowReal && j <= m2) {
                                float ix1 = fmaxf(rx1, r2x1[j-1]), iy1 = fmaxf(ry1, r2y1[j-1]);
                                float ix2 = fminf(rx2, r2x2[j-1]), iy2 = fminf(ry2, r2y2[j-1]);
                                float iw = fmaxf(ix2 - ix1, 0.f), ih = fmaxf(iy2 - iy1, 0.f);
                                float inter = iw * ih;
                                cost = -(inter / (ra + r2a[j-1] - inter));
                            }
                            float cur = cost - u0 - varr[j];
                            if (cur < minvarr[j]) { minvarr[j] = cur; wayarr[j] = j0; }
                        }
                    }
                    __syncthreads();

                    float bv = INFINITY; int bu = 0, bj = n + 1;
                    for (int j = lane; j <= n; j += 64) {
                        float m = usedarr[j] ? INFINITY : minvarr[j];
                        int   un = (parr[j] == 0) ? 1 : 0;
                        if (m < bv || (m == bv && (un > bu || (un == bu && j < bj))))
                            { bv = m; bu = un; bj = j; }
                    }
                    #pragma unroll
                    for (int off = 32; off; off >>= 1) {
                        float ov = __shfl_xor(bv, off);
                        int   ou = __shfl_xor(bu, off);
                        int   oj = __shfl_xor(bj, off);
                        if (ov < bv || (ov == bv && (ou > bu || (ou == bu && oj < bj))))
                            { bv = ov; bu = ou; bj = oj; }
                    }
                    j0 = bj;
                    const float delta = bv;
                    for (int j = lane; j <= n; j += 64) {
                        if (usedarr[j]) { uarr[parr[j]] += delta; varr[j] -= delta; }
                        else            { minvarr[j] -= delta; }
                    }
                    __syncthreads();
                    if (parr[j0] == 0) break;
                }

                if (lane == 0) {
                    int jj = j0, guard = 0;
                    while (jj != 0 && guard++ <= n + 1) {
                        int j1 = wayarr[jj];
                        parr[jj] = parr[j1];
                        jj = j1;
                    }
                }
                __syncthreads();
            }

            float contrib = 0.f;
            for (int j = lane; j <= n; j += 64) {
                if (j >= 1 && j <= m2) {
                    int pi = parr[j];
                    if (pi >= 1 && pi <= m1) {
                        float ix1 = fmaxf(r1x1[pi-1], r2x1[j-1]), iy1 = fmaxf(r1y1[pi-1], r2y1[j-1]);
                        float ix2 = fminf(r1x2[pi-1], r2x2[j-1]), iy2 = fminf(r1y2[pi-1], r2y2[j-1]);
                        float iw = fmaxf(ix2 - ix1, 0.f), ih = fmaxf(iy2 - iy1, 0.f);
                        float inter = iw * ih;
                        contrib += inter / (r1a[pi-1] + r2a[j-1] - inter);
                    }
                }
            }
            #pragma unroll
            for (int off = 32; off; off >>= 1) contrib += __shfl_xor(contrib, off);
            blockContrib = contrib;
        }
    } while (0);

    // ---- tail: publish partials; workers release flag, block 0 finalizes
    if (lane == 0) {
        sum_part[blk] = blockContrib;
        m1_part[blk]  = m1;
        m2_part[blk]  = m2;
    }
    if (blk != 0) {
        if (lane == 0)
            __hip_atomic_store(&flags[blk], 1, __ATOMIC_RELEASE, __HIP_MEMORY_SCOPE_AGENT);
        return;
    }

    // block 0: acquire-poll the other 39 flags (poison 0xAA != 1)
    if (lane >= 1 && lane < NBLK) {
        while (__hip_atomic_load(&flags[lane], __ATOMIC_ACQUIRE,
                                 __HIP_MEMORY_SCOPE_AGENT) != 1)
            __builtin_amdgcn_s_sleep(1);
    }
    float s = 0.f; int a1 = 0, a2 = 0;
    if (lane < NBLK) { s = sum_part[lane]; a1 = m1_part[lane]; a2 = m2_part[lane]; }
    float st = s; int t1 = a1, t2 = a2;
    #pragma unroll
    for (int k = 1; k < NCLS; ++k) {
        st += __shfl(s, lane + k);
        t1 += __shfl(a1, lane + k);
        t2 += __shfl(a2, lane + k);
    }
    float per;
    {
        float denom = fmaxf(fmaxf((float)t1, (float)t2), 1.f);
        float pv = 1.f - st / denom;
        bool bz = (t1 == 0) && (t2 == 0);
        bool oz = ((t1 == 0) != (t2 == 0));
        per = bz ? 0.f : (oz ? 1.f : pv);
    }
    float acc = 0.f;
    #pragma unroll
    for (int bb = 0; bb < BIMG; ++bb) acc += __shfl(per, bb * NCLS);
    if (lane == 0) out[0] = acc / (float)BIMG;
}

extern "C" void kernel_launch(void* const* d_in, const int* in_sizes, int n_in,
                              void* d_out, int out_size, void* d_ws, size_t ws_size,
                              hipStream_t stream) {
    const float* b1 = (const float*)d_in[0];
    const float* b2 = (const float*)d_in[1];
    float* sum_part = (float*)d_ws;                 // [40] f32
    int*   m1_part  = (int*)(sum_part + NBLK);      // [40] i32
    int*   m2_part  = m1_part + NBLK;               // [40] i32
    int*   flags    = m2_part + NBLK;               // [40] i32 (poisoned != 1)

    det_fused_kernel<<<NBLK, 64, 0, stream>>>(b1, b2, sum_part, m1_part, m2_part,
                                              flags, (float*)d_out);
}